// Round 3
// baseline (78.490 us; speedup 1.0000x reference)
//
#include <hip/hip_runtime.h>
#include <hip/hip_bf16.h>

#define BB 2
#define NN 512
#define CC 128
#define UU 128
// output row stride = UNITS + 2C = 384

__device__ __forceinline__ float bfraw(unsigned short u) {
    return __uint_as_float(((unsigned int)u) << 16);
}

__global__ __launch_bounds__(128) void edgeconv_kernel(
    const void* __restrict__ inputs_,   // [B,N,C]   f32 (bf16 fallback)
    const void* __restrict__ adj_,      // [B,N,N]
    const int*  __restrict__ xidx,      // [B,N]     int32
    const void* __restrict__ w_,        // [2C,UNITS]
    const void* __restrict__ bias_,     // [UNITS]
    void*       __restrict__ out_)      // [B,N,UNITS+2C]
{
    const int row  = blockIdx.x;      // b*NN + i
    const int t    = threadIdx.x;     // 0..127
    const int lane = t & 63;
    const int wv   = t >> 6;

    __shared__ float  x_sh[CC];
    __shared__ float4 pp[4][32];      // p partials [cg][tg]
    __shared__ float4 qq[4][32];      // q partials [cg][tg]
    __shared__ float  wred[2];
    __shared__ int    wdet[2];
    __shared__ int    wz0[2], wzA[2];
    __shared__ float  s_sh;

    // ---- dtype detection: true-f32 adj contains ONLY exact 0.0f/1.0f in its
    // first 256 words; bf16 data reinterpreted as f32 fails this w.h.p.
    {
        const float* pf = (const float*)adj_;
        const float v0 = pf[2 * t], v1 = pf[2 * t + 1];
        const bool ok = (v0 == 0.f || v0 == 1.f) && (v1 == 0.f || v1 == 1.f);
        const unsigned long long bm = __ballot(ok);
        if (lane == 0) wdet[wv] = (bm == 0xFFFFFFFFFFFFFFFFULL) ? 1 : 0;
    }
    __syncthreads();
    const bool isf32 = (wdet[0] & wdet[1]) != 0;   // uniform across block

    // ---- stage x, degree partials, s ----
    float x_c, d;
    if (isf32) {
        x_c = ((const float*)inputs_)[row * CC + t];
        const float* arow = (const float*)adj_ + (size_t)row * NN;
        const float4 a4 = *reinterpret_cast<const float4*>(arow + 4 * t);
        d = a4.x + a4.y + a4.z + a4.w;
        if (t == 0) s_sh = arow[xidx[row]];
    } else {
        x_c = bfraw(((const unsigned short*)inputs_)[row * CC + t]);
        const unsigned short* arow = (const unsigned short*)adj_ + (size_t)row * NN;
        const ushort4 a4 = *reinterpret_cast<const ushort4*>(arow + 4 * t);
        d = bfraw(a4.x) + bfraw(a4.y) + bfraw(a4.z) + bfraw(a4.w);
        if (t == 0) s_sh = bfraw(arow[xidx[row]]);
    }
    x_sh[t] = x_c;
    #pragma unroll
    for (int off = 32; off > 0; off >>= 1) d += __shfl_down(d, off);
    if (lane == 0) wred[wv] = d;
    __syncthreads();

    const float deg = wred[0] + wred[1];
    const float s   = s_sh;

    // ---- p[u] = sum_c x[c]*w[c,u];  q[u] = sum_c x[c]*w[C+c,u] ----
    float p, q;
    if (isf32) {
        // cooperative: tg owns units [4tg,4tg+4); cg owns c in [32cg,32cg+32)
        const int tg = t & 31, cg = t >> 5;
        const float4* w4 = (const float4*)w_;       // [256 rows][32 float4]
        float4 pa = {0.f, 0.f, 0.f, 0.f}, qa = {0.f, 0.f, 0.f, 0.f};
        const int c0 = cg << 5;
        #pragma unroll 8
        for (int cc = 0; cc < 32; ++cc) {
            const int c = c0 + cc;
            const float xc = x_sh[c];
            const float4 w1 = w4[c * 32 + tg];
            const float4 w2 = w4[(c + 128) * 32 + tg];
            pa.x = fmaf(xc, w1.x, pa.x);  pa.y = fmaf(xc, w1.y, pa.y);
            pa.z = fmaf(xc, w1.z, pa.z);  pa.w = fmaf(xc, w1.w, pa.w);
            qa.x = fmaf(xc, w2.x, qa.x);  qa.y = fmaf(xc, w2.y, qa.y);
            qa.z = fmaf(xc, w2.z, qa.z);  qa.w = fmaf(xc, w2.w, qa.w);
        }
        pp[cg][tg] = pa;  qq[cg][tg] = qa;
        __syncthreads();
        const float* ppf = (const float*)pp;        // ppf[cg*128 + u]
        const float* qqf = (const float*)qq;
        p = ppf[t] + ppf[128 + t] + ppf[256 + t] + ppf[384 + t];
        q = qqf[t] + qqf[128 + t] + qqf[256 + t] + qqf[384 + t];
    } else {
        p = 0.f; q = 0.f;
        const unsigned short* w1 = (const unsigned short*)w_ + t;
        const unsigned short* w2 = w1 + CC * UU;
        #pragma unroll 8
        for (int c = 0; c < CC; ++c) {
            const float xc = x_sh[c];
            p = fmaf(xc, bfraw(w1[c * UU]), p);
            q = fmaf(xc, bfraw(w2[c * UU]), q);
        }
    }
    const float bo = isf32 ? ((const float*)bias_)[t]
                           : bfraw(((const unsigned short*)bias_)[t]);

    // ---- the three distinct per-j out values at unit t ----
    const float pa_ = (s > 0.5f) ? p : (p - q);  // a=1: s=1 -> p, s=0 -> p-q
    const float v0 = fmaxf(bo, 0.f);             // a=0 rows
    const float vA = fmaxf(pa_ + bo, 0.f);       // a=1 rows

    // ---- block-wide "any unit nonzero" per category ----
    const unsigned long long m0 = __ballot(v0 > 0.f);
    const unsigned long long mA = __ballot(vA > 0.f);
    if (lane == 0) { wz0[wv] = (m0 != 0ULL); wzA[wv] = (mA != 0ULL); }
    __syncthreads();

    const int z0 = wz0[0] | wz0[1];
    const int zA = wzA[0] | wzA[1];
    const float ndeg = (float)NN - deg;
    const float n = ndeg * (z0 ? 1.f : 0.f) + deg * (zA ? 1.f : 0.f);

    // ---- maxpool over j: max of the categories present ----
    float maxp;
    if (deg > 0.5f) maxp = (ndeg > 0.5f) ? fmaxf(v0, vA) : vA;
    else            maxp = v0;

    // ---- avgpool: [deg*x, deg*(s-1)*x] / n ----
    const float a1 = deg * x_c / n;
    const float a2 = deg * (s - 1.f) * x_c / n;

    if (isf32) {
        float* orow = (float*)out_ + (size_t)row * (UU + 2 * CC);
        orow[t]           = maxp;
        orow[UU + t]      = a1;
        orow[UU + CC + t] = a2;
    } else {
        __hip_bfloat16* orow = (__hip_bfloat16*)out_ + (size_t)row * (UU + 2 * CC);
        orow[t]           = __float2bfloat16(maxp);
        orow[UU + t]      = __float2bfloat16(a1);
        orow[UU + CC + t] = __float2bfloat16(a2);
    }
}

extern "C" void kernel_launch(void* const* d_in, const int* in_sizes, int n_in,
                              void* d_out, int out_size, void* d_ws, size_t ws_size,
                              hipStream_t stream) {
    const void* inputs = d_in[0];
    const void* adjm   = d_in[1];
    const int*  xidx   = (const int*)d_in[2];
    const void* w      = d_in[3];
    const void* bias   = d_in[4];

    edgeconv_kernel<<<BB * NN, 128, 0, stream>>>(inputs, adjm, xidx, w, bias, d_out);
}

// Round 4
// 69.574 us; speedup vs baseline: 1.1281x; 1.1281x over previous
//
#include <hip/hip_runtime.h>
#include <hip/hip_bf16.h>

#define BB 2
#define NN 512
#define CC 128
#define UU 128
// output row stride = UNITS + 2C = 384

__device__ __forceinline__ float bfraw(unsigned short u) {
    return __uint_as_float(((unsigned int)u) << 16);
}

__global__ __launch_bounds__(128) void edgeconv_kernel(
    const void* __restrict__ inputs_,   // [B,N,C]   f32 (bf16 fallback)
    const void* __restrict__ adj_,      // [B,N,N]
    const int*  __restrict__ xidx,      // [B,N]     int32
    const void* __restrict__ w_,        // [2C,UNITS]
    const void* __restrict__ bias_,     // [UNITS]
    void*       __restrict__ out_)      // [B,N,UNITS+2C]
{
    const int row  = blockIdx.x;      // b*NN + i
    const int t    = threadIdx.x;     // 0..127 (unit o == channel c == t)
    const int lane = t & 63;
    const int wv   = t >> 6;

    __shared__ float x_sh[CC];
    __shared__ float wred[2];
    __shared__ int   wdet[2];
    __shared__ int   wz0[2], wzA[2];
    __shared__ float s_sh;

    // ---- dtype detection: true-f32 adj contains ONLY exact 0.0f/1.0f in its
    // first 256 words; bf16 data reinterpreted as f32 fails this w.h.p.
    {
        const float* pf = (const float*)adj_;
        const float v0 = pf[2 * t], v1 = pf[2 * t + 1];
        const bool ok = (v0 == 0.f || v0 == 1.f) && (v1 == 0.f || v1 == 1.f);
        const unsigned long long bm = __ballot(ok);
        if (lane == 0) wdet[wv] = (bm == 0xFFFFFFFFFFFFFFFFULL) ? 1 : 0;
    }

    // ---- stage x, degree partials, s ----
    float x_c, d;
    {
        // speculative f32 loads (correct path per detection below; bf16 path
        // reloads). Detection flag is read after the same __syncthreads().
    }
    __syncthreads();
    const bool isf32 = (wdet[0] & wdet[1]) != 0;   // uniform across block

    if (isf32) {
        x_c = ((const float*)inputs_)[row * CC + t];
        const float* arow = (const float*)adj_ + (size_t)row * NN;
        const float4 a4 = *reinterpret_cast<const float4*>(arow + 4 * t);
        d = a4.x + a4.y + a4.z + a4.w;
        if (t == 0) s_sh = arow[xidx[row]];
    } else {
        x_c = bfraw(((const unsigned short*)inputs_)[row * CC + t]);
        const unsigned short* arow = (const unsigned short*)adj_ + (size_t)row * NN;
        const ushort4 a4 = *reinterpret_cast<const ushort4*>(arow + 4 * t);
        d = bfraw(a4.x) + bfraw(a4.y) + bfraw(a4.z) + bfraw(a4.w);
        if (t == 0) s_sh = bfraw(arow[xidx[row]]);
    }
    x_sh[t] = x_c;
    #pragma unroll
    for (int off = 32; off > 0; off >>= 1) d += __shfl_down(d, off);
    if (lane == 0) wred[wv] = d;
    __syncthreads();

    const float deg = wred[0] + wred[1];
    const float s   = s_sh;

    // ---- p[t] = sum_c x_c*w[c,t];  q[t] = sum_c x_c*w[C+c,t] ----
    // Per-wave the 64 lanes read 64 consecutive floats of row c -> coalesced;
    // w is 128 KB and L2-resident after the first blocks.
    float p = 0.f, q = 0.f, bo;
    if (isf32) {
        const float* w1 = (const float*)w_ + t;
        const float* w2 = w1 + CC * UU;
        #pragma unroll 8
        for (int c = 0; c < CC; ++c) {
            const float xc = x_sh[c];
            p = fmaf(xc, w1[c * UU], p);
            q = fmaf(xc, w2[c * UU], q);
        }
        bo = ((const float*)bias_)[t];
    } else {
        const unsigned short* w1 = (const unsigned short*)w_ + t;
        const unsigned short* w2 = w1 + CC * UU;
        #pragma unroll 8
        for (int c = 0; c < CC; ++c) {
            const float xc = x_sh[c];
            p = fmaf(xc, bfraw(w1[c * UU]), p);
            q = fmaf(xc, bfraw(w2[c * UU]), q);
        }
        bo = bfraw(((const unsigned short*)bias_)[t]);
    }

    // ---- the three distinct per-j out values at unit t ----
    const float pa = (s > 0.5f) ? p : (p - q);   // a=1: s=1 -> p, s=0 -> p-q
    const float v0 = fmaxf(bo, 0.f);             // a=0 rows
    const float vA = fmaxf(pa + bo, 0.f);        // a=1 rows

    // ---- block-wide "any unit nonzero" per category ----
    const unsigned long long m0 = __ballot(v0 > 0.f);
    const unsigned long long mA = __ballot(vA > 0.f);
    if (lane == 0) { wz0[wv] = (m0 != 0ULL); wzA[wv] = (mA != 0ULL); }
    __syncthreads();

    const int z0 = wz0[0] | wz0[1];
    const int zA = wzA[0] | wzA[1];
    const float ndeg = (float)NN - deg;
    const float n = ndeg * (z0 ? 1.f : 0.f) + deg * (zA ? 1.f : 0.f);

    // ---- maxpool over j: max of the categories present ----
    float maxp;
    if (deg > 0.5f) maxp = (ndeg > 0.5f) ? fmaxf(v0, vA) : vA;
    else            maxp = v0;

    // ---- avgpool: [deg*x, deg*(s-1)*x] / n ----
    const float a1 = deg * x_c / n;
    const float a2 = deg * (s - 1.f) * x_c / n;

    if (isf32) {
        float* orow = (float*)out_ + (size_t)row * (UU + 2 * CC);
        orow[t]           = maxp;
        orow[UU + t]      = a1;
        orow[UU + CC + t] = a2;
    } else {
        __hip_bfloat16* orow = (__hip_bfloat16*)out_ + (size_t)row * (UU + 2 * CC);
        orow[t]           = __float2bfloat16(maxp);
        orow[UU + t]      = __float2bfloat16(a1);
        orow[UU + CC + t] = __float2bfloat16(a2);
    }
}

extern "C" void kernel_launch(void* const* d_in, const int* in_sizes, int n_in,
                              void* d_out, int out_size, void* d_ws, size_t ws_size,
                              hipStream_t stream) {
    const void* inputs = d_in[0];
    const void* adjm   = d_in[1];
    const int*  xidx   = (const int*)d_in[2];
    const void* w      = d_in[3];
    const void* bias   = d_in[4];

    edgeconv_kernel<<<BB * NN, 128, 0, stream>>>(inputs, adjm, xidx, w, bias, d_out);
}

// Round 5
// 68.820 us; speedup vs baseline: 1.1405x; 1.0110x over previous
//
#include <hip/hip_runtime.h>
#include <hip/hip_bf16.h>

#define BB 2
#define NN 512
#define CC 128
#define UU 128
// output row stride = UNITS + 2C = 384; rows per block = 2

__global__ __launch_bounds__(256) void edgeconv_kernel(
    const float* __restrict__ inputs,   // [B,N,C]
    const float* __restrict__ adj,      // [B,N,N]
    const int*   __restrict__ xidx,     // [B,N]
    const float* __restrict__ w,        // [2C,UNITS] flat
    const float* __restrict__ bias,     // [UNITS]
    float*       __restrict__ out)      // [B,N,UNITS+2C]
{
    const int r0   = blockIdx.x * 2;    // flat row index b*NN+i (N even -> same b)
    const int t    = threadIdx.x;       // 0..255
    const int u    = t & 127;           // unit / channel
    const int h    = t >> 7;            // 0 -> w1 (p), 1 -> w2 (q); also "my row" later
    const int wave = t >> 6;            // 0..3
    const int lane = t & 63;

    __shared__ float x_sh[2][CC];       // x rows
    __shared__ float pq[2][2][UU];      // [row][h][u] matvec results
    __shared__ float wred[4][2];        // per-wave degree partials [wave][row]
    __shared__ float s_sh[2];
    __shared__ int   wzA[4], wz0[4];

    // ---- stage x rows: x_sh[h][u] = inputs[(r0+h)*C + u] ----
    x_sh[h][u] = inputs[(r0 + h) * CC + u];

    // ---- degree partials: 512 adj vals per row, float2 per thread ----
    const float* arow0 = adj + (size_t)r0 * NN;
    const float* arow1 = arow0 + NN;
    const float2 a0 = reinterpret_cast<const float2*>(arow0)[t];
    const float2 a1 = reinterpret_cast<const float2*>(arow1)[t];
    float d0 = a0.x + a0.y;
    float d1 = a1.x + a1.y;
    #pragma unroll
    for (int off = 32; off > 0; off >>= 1) {
        d0 += __shfl_down(d0, off);
        d1 += __shfl_down(d1, off);
    }
    if (lane == 0) { wred[wave][0] = d0; wred[wave][1] = d1; }

    // ---- s = adj[row, xidx[row]] ----
    if (t == 0) s_sh[0] = arow0[xidx[r0]];
    if (t == 1) s_sh[1] = arow1[xidx[r0 + 1]];
    __syncthreads();

    // ---- matvec: group h computes col u of x_row · w_h for BOTH rows ----
    // w element loaded once, used twice (row reuse) -> w L2 traffic halves.
    const float* wcol = w + h * (CC * UU) + u;   // w[(h*C + c)*U + u]
    float acc0 = 0.f, acc1 = 0.f;
    #pragma unroll 8
    for (int c = 0; c < CC; ++c) {
        const float wv = wcol[c * UU];           // coalesced 256B per wave
        acc0 = fmaf(x_sh[0][c], wv, acc0);       // LDS broadcast reads
        acc1 = fmaf(x_sh[1][c], wv, acc1);
    }
    pq[0][h][u] = acc0;
    pq[1][h][u] = acc1;
    __syncthreads();

    // ---- group h now owns output row r0+h ----
    const float p   = pq[h][0][u];
    const float q   = pq[h][1][u];
    const float s   = s_sh[h];
    const float deg = wred[0][h] + wred[1][h] + wred[2][h] + wred[3][h];
    const float bo  = bias[u];

    const float pa = (s > 0.5f) ? p : (p - q);   // a=1: s=1 -> p, s=0 -> p-q
    const float v0 = fmaxf(bo, 0.f);             // a=0 rows (row-independent)
    const float vA = fmaxf(pa + bo, 0.f);        // a=1 rows

    const unsigned long long mA = __ballot(vA > 0.f);
    const unsigned long long m0 = __ballot(v0 > 0.f);
    if (lane == 0) { wzA[wave] = (mA != 0ULL); wz0[wave] = (m0 != 0ULL); }
    __syncthreads();

    const int zA = h ? (wzA[2] | wzA[3]) : (wzA[0] | wzA[1]);
    const int z0 = wz0[0] | wz0[1] | wz0[2] | wz0[3];   // same for both rows
    const float ndeg = (float)NN - deg;
    const float n = ndeg * (z0 ? 1.f : 0.f) + deg * (zA ? 1.f : 0.f);

    float maxp;
    if (deg > 0.5f) maxp = (ndeg > 0.5f) ? fmaxf(v0, vA) : vA;
    else            maxp = v0;

    const float xc = x_sh[h][u];
    const float inv_n = 1.f / n;
    float* orow = out + (size_t)(r0 + h) * (UU + 2 * CC);
    orow[u]            = maxp;
    orow[UU + u]       = deg * xc * inv_n;
    orow[UU + CC + u]  = deg * (s - 1.f) * xc * inv_n;
}

extern "C" void kernel_launch(void* const* d_in, const int* in_sizes, int n_in,
                              void* d_out, int out_size, void* d_ws, size_t ws_size,
                              hipStream_t stream) {
    const float* inputs = (const float*)d_in[0];
    const float* adjm   = (const float*)d_in[1];
    const int*   xidx   = (const int*)d_in[2];
    const float* w      = (const float*)d_in[3];
    const float* bias   = (const float*)d_in[4];
    float*       out    = (float*)d_out;

    edgeconv_kernel<<<(BB * NN) / 2, 256, 0, stream>>>(inputs, adjm, xidx, w, bias, out);
}